// Round 1
// baseline (24.552 us; speedup 1.0000x reference)
//
#include <hip/hip_runtime.h>
#include <math.h>

// Problem: RelativeDepthLoss — H=W=64, N=4096, f32 in, f32 scalar out.
// ws float layout: [0]=grad_num, [1]=mask_sum, [2]=pair_sum (zeroed by kgrad each call)

#define HH 64
#define WW 64
#define NN 4096

// Kernel 1: d = pred-gt in LDS; sobel (zero-pad) on d; masked grad sum + mask count.
// Single block of 256 threads — 4096 px, trivial.
__global__ __launch_bounds__(256) void kgrad(const float* __restrict__ pred,
                                             const float* __restrict__ gt,
                                             const int* __restrict__ mask,
                                             float* __restrict__ ws) {
    __shared__ float d[NN];
    __shared__ float red[8];
    const int t = threadIdx.x;
    for (int k = t; k < NN; k += 256) d[k] = pred[k] - gt[k];
    __syncthreads();

    float gsum = 0.f, msum = 0.f;
    for (int k = t; k < NN; k += 256) {
        const int r = k >> 6, c = k & 63;
        const float x00 = (r > 0  && c > 0 ) ? d[k - 65] : 0.f;
        const float x01 = (r > 0           ) ? d[k - 64] : 0.f;
        const float x02 = (r > 0  && c < 63) ? d[k - 63] : 0.f;
        const float x10 = (           c > 0 ) ? d[k - 1 ] : 0.f;
        const float x12 = (           c < 63) ? d[k + 1 ] : 0.f;
        const float x20 = (r < 63 && c > 0 ) ? d[k + 63] : 0.f;
        const float x21 = (r < 63          ) ? d[k + 64] : 0.f;
        const float x22 = (r < 63 && c < 63) ? d[k + 65] : 0.f;
        // cross-correlation (no kernel flip), applied to d by linearity
        const float gx = (x02 - x00) + 2.f * (x12 - x10) + (x22 - x20);
        const float gy = (x20 - x00) + 2.f * (x21 - x01) + (x22 - x02);
        const float m  = (mask[k] != 0) ? 1.f : 0.f;
        gsum += m * (fabsf(gx) + fabsf(gy));
        msum += m;
    }
    // wave64 reduce
    for (int off = 32; off > 0; off >>= 1) {
        gsum += __shfl_down(gsum, off, 64);
        msum += __shfl_down(msum, off, 64);
    }
    const int wv = t >> 6;
    if ((t & 63) == 0) { red[wv] = gsum; red[4 + wv] = msum; }
    __syncthreads();
    if (t == 0) {
        ws[0] = red[0] + red[1] + red[2] + red[3];
        ws[1] = red[4] + red[5] + red[6] + red[7];
        ws[2] = 0.f;   // pair accumulator — re-zeroed every call (no cross-call state)
    }
}

// Kernel 2: pairwise sum. Grid = 16 i-tiles x 16 j-tiles (256 blocks, 256 thr).
// Each thread owns one i, loops the 256-j chunk staged in LDS.
// |d_i - d_j| / (sqrt(dr^2+dc^2)+0.001) via a 64x64 reciprocal-distance table.
__global__ __launch_bounds__(256) void kpair(const float* __restrict__ pred,
                                             const float* __restrict__ gt,
                                             const int* __restrict__ mask,
                                             float* __restrict__ ws) {
    __shared__ float dj[256];
    __shared__ float wj[256];
    __shared__ float tbl[64 * 64];
    __shared__ float red[4];
    const int t  = threadIdx.x;
    const int bi = blockIdx.x >> 4;
    const int bj = blockIdx.x & 15;
    const int j0 = bj << 8;

    const int jg = j0 + t;
    dj[t] = pred[jg] - gt[jg];
    wj[t] = (mask[jg] != 0) ? 1.f : 0.f;
    for (int k = t; k < 64 * 64; k += 256) {
        const float dr = (float)(k >> 6), dc = (float)(k & 63);
        tbl[k] = 1.f / (sqrtf(dr * dr + dc * dc) + 0.001f);
    }
    __syncthreads();

    const int   i  = (bi << 8) + t;
    const float di = pred[i] - gt[i];
    const float wi = (mask[i] != 0) ? 1.f : 0.f;
    const int   ri = i >> 6, ci = i & 63;

    float acc = 0.f;
#pragma unroll 8
    for (int jj = 0; jj < 256; ++jj) {
        const int j  = j0 + jj;
        const int dr = abs(ri - (j >> 6));
        const int dc = abs(ci - (j & 63));
        acc += wj[jj] * fabsf(di - dj[jj]) * tbl[(dr << 6) + dc];
    }
    acc *= wi;

    for (int off = 32; off > 0; off >>= 1) acc += __shfl_down(acc, off, 64);
    if ((t & 63) == 0) red[t >> 6] = acc;
    __syncthreads();
    if (t == 0) atomicAdd(&ws[2], red[0] + red[1] + red[2] + red[3]);
}

// Kernel 3: finalize scalar.
__global__ void kfinal(const float* __restrict__ ws, float* __restrict__ out) {
    const float msum      = ws[1];
    const float grad_loss = ws[0] / msum;
    const float pair_loss = ws[2] / sqrtf(msum * msum + 1e-5f);
    const float total     = 0.5f * grad_loss + 0.5f * pair_loss;  // weight = 0.5
    out[0] = logf(total + 1.f);
}

extern "C" void kernel_launch(void* const* d_in, const int* in_sizes, int n_in,
                              void* d_out, int out_size, void* d_ws, size_t ws_size,
                              hipStream_t stream) {
    const float* pred = (const float*)d_in[0];
    const float* gt   = (const float*)d_in[1];
    const int*   msk  = (const int*)d_in[2];
    float* ws  = (float*)d_ws;
    float* out = (float*)d_out;

    kgrad <<<1,   256, 0, stream>>>(pred, gt, msk, ws);
    kpair <<<256, 256, 0, stream>>>(pred, gt, msk, ws);
    kfinal<<<1,   1,   0, stream>>>(ws, out);
}

// Round 2
// 23.172 us; speedup vs baseline: 1.0595x; 1.0595x over previous
//
#include <hip/hip_runtime.h>
#include <math.h>

// RelativeDepthLoss — H=W=64, N=4096, f32 in, f32 scalar out.
// One fused kernel (257 blocks):
//   blocks 0..255 : pairwise tiles. block = (ib,jb) = 256-i x 256-j tile.
//                   i-tile = rows [4ib,4ib+4), j-tile = rows [4jb,4jb+4).
//                   dr = ri-rj spans only 7 values -> 7x128 mirrored LDS table
//                   tbl[s*128 + 63 + (cj-ci)] = 1/(sqrt(dr^2+dc^2)+0.001),
//                   so the inner loop is pure immediate-offset LDS reads:
//                   per pair: ds_read_b32(tbl) + ds_read_b64(djw bcast) + sub/mul/fma.
//   block 256     : sobel-gradient masked sum (linearity: sobel(p)-sobel(g)=sobel(p-g)).
//   last finished block (atomic counter) computes the scalar and writes d_out.
// ws floats: [0]=pair_sum [1]=grad_num [2]=mask_sum [3]=counter(u32). Zeroed by
// a 16B hipMemsetAsync each call (graph-capturable; no cross-call state).

#define NPAIRBLK 256
#define TOTALBLK 257

__global__ __launch_bounds__(256) void fused(const float* __restrict__ pred,
                                             const float* __restrict__ gt,
                                             const int* __restrict__ mask,
                                             float* __restrict__ ws,
                                             float* __restrict__ out) {
    const int t   = threadIdx.x;
    const int blk = blockIdx.x;

    float myPair = 0.f, myGrad = 0.f, myMask = 0.f;   // this block's partials

    if (blk < NPAIRBLK) {
        __shared__ float  tbl[7 * 128];
        __shared__ float2 djw[256];
        __shared__ float  redp[4];

        const int ib = blk >> 4, jb = blk & 15;
        const int drmin = 4 * (ib - jb) - 3;

        // stage j-chunk: (pred-gt, mask) packed
        const int jg = (jb << 8) + t;
        djw[t] = make_float2(pred[jg] - gt[jg], (mask[jg] != 0) ? 1.f : 0.f);

        // mirrored reciprocal-distance table (exact: sqrt + real div, 896 entries)
        for (int k = t; k < 7 * 128; k += 256) {
            const int   s   = k >> 7;
            const float dr  = (float)(s + drmin);
            const float dc  = (float)((k & 127) - 63);
            tbl[k] = 1.f / (sqrtf(dr * dr + dc * dc) + 0.001f);
        }
        __syncthreads();

        const int   ig = (ib << 8) + t;
        const float di = pred[ig] - gt[ig];
        const float wi = (mask[ig] != 0) ? 1.f : 0.f;
        const int   ci = t & 63;
        const int   tr = t >> 6;

        float acc = 0.f;
        for (int jr = 0; jr < 4; ++jr) {
            const int s = tr - jr + 3;                    // in [0,6]
            const float*  trow = &tbl[(s << 7) + 63 - ci]; // + cj walks imm offsets
            const float2* djr  = &djw[jr << 6];            // broadcast, imm offsets
#pragma unroll 16
            for (int cj = 0; cj < 64; ++cj) {
                const float2 dw = djr[cj];
                acc += fabsf(di - dw.x) * (dw.y * trow[cj]);
            }
        }
        acc *= wi;

        for (int off = 32; off > 0; off >>= 1) acc += __shfl_down(acc, off, 64);
        if ((t & 63) == 0) redp[t >> 6] = acc;
        __syncthreads();
        if (t == 0) myPair = redp[0] + redp[1] + redp[2] + redp[3];
    } else {
        // ---- gradient block ----
        __shared__ float d[4096];
        __shared__ float redg[8];
        for (int k = t; k < 4096; k += 256) d[k] = pred[k] - gt[k];
        __syncthreads();

        float gsum = 0.f, msum = 0.f;
        for (int k = t; k < 4096; k += 256) {
            const int r = k >> 6, c = k & 63;
            const float x00 = (r > 0  && c > 0 ) ? d[k - 65] : 0.f;
            const float x01 = (r > 0           ) ? d[k - 64] : 0.f;
            const float x02 = (r > 0  && c < 63) ? d[k - 63] : 0.f;
            const float x10 = (          c > 0 ) ? d[k - 1 ] : 0.f;
            const float x12 = (          c < 63) ? d[k + 1 ] : 0.f;
            const float x20 = (r < 63 && c > 0 ) ? d[k + 63] : 0.f;
            const float x21 = (r < 63          ) ? d[k + 64] : 0.f;
            const float x22 = (r < 63 && c < 63) ? d[k + 65] : 0.f;
            const float gx = (x02 - x00) + 2.f * (x12 - x10) + (x22 - x20);
            const float gy = (x20 - x00) + 2.f * (x21 - x01) + (x22 - x02);
            const float m  = (mask[k] != 0) ? 1.f : 0.f;
            gsum += m * (fabsf(gx) + fabsf(gy));
            msum += m;
        }
        for (int off = 32; off > 0; off >>= 1) {
            gsum += __shfl_down(gsum, off, 64);
            msum += __shfl_down(msum, off, 64);
        }
        if ((t & 63) == 0) { redg[t >> 6] = gsum; redg[4 + (t >> 6)] = msum; }
        __syncthreads();
        if (t == 0) {
            myGrad = redg[0] + redg[1] + redg[2] + redg[3];
            myMask = redg[4] + redg[5] + redg[6] + redg[7];
        }
    }

    // ---- publish partials; last block finalizes ----
    if (t == 0) {
        if (blk < NPAIRBLK) {
            atomicAdd(&ws[0], myPair);
        } else {
            atomicAdd(&ws[1], myGrad);
            atomicAdd(&ws[2], myMask);
        }
        __threadfence();
        const unsigned old = atomicAdd((unsigned*)(ws + 3), 1u);
        if (old == TOTALBLK - 1) {
            // coherent reads via atomic fetch-add(0)
            const float pair = atomicAdd(&ws[0], 0.f);
            const float gnum = atomicAdd(&ws[1], 0.f);
            const float msum = atomicAdd(&ws[2], 0.f);
            const float grad_loss = gnum / msum;
            const float pair_loss = pair / sqrtf(msum * msum + 1e-5f);
            out[0] = logf(0.5f * grad_loss + 0.5f * pair_loss + 1.f);
        }
    }
}

extern "C" void kernel_launch(void* const* d_in, const int* in_sizes, int n_in,
                              void* d_out, int out_size, void* d_ws, size_t ws_size,
                              hipStream_t stream) {
    const float* pred = (const float*)d_in[0];
    const float* gt   = (const float*)d_in[1];
    const int*   msk  = (const int*)d_in[2];
    float* ws  = (float*)d_ws;
    float* out = (float*)d_out;

    hipMemsetAsync(d_ws, 0, 16, stream);               // zero accumulators+counter
    fused<<<TOTALBLK, 256, 0, stream>>>(pred, gt, msk, ws, out);
}